// Round 15
// baseline (194.473 us; speedup 1.0000x reference)
//
#include <hip/hip_runtime.h>
#include <hip/hip_bf16.h>

#define D_MODEL 1024
#define N_HEADS 16
#define HEAD_DIM 64
#define SEQ 2048
#define BATCH 2

typedef __attribute__((ext_vector_type(8))) short bf16x8;
typedef __attribute__((ext_vector_type(4))) short bf16x4;
typedef __attribute__((ext_vector_type(4))) float f32x4;
typedef __attribute__((ext_vector_type(16))) float f32x16;

typedef __attribute__((address_space(3))) unsigned lds_uint;
typedef __attribute__((address_space(1))) const unsigned global_cuint;

__device__ __forceinline__ void async_cp16(const ushort* g, ushort* l) {
  __builtin_amdgcn_global_load_lds((global_cuint*)g, (lds_uint*)l, 16, 0, 0);
}

__device__ __forceinline__ ushort f2b(float f) {
  union { float f; unsigned u; } x; x.f = f;
  unsigned r = x.u + 0x7fffu + ((x.u >> 16) & 1u);
  return (ushort)(r >> 16);
}

// packed f32x2 -> bf16x2; low word = a
__device__ __forceinline__ unsigned pk2(float a, float b) {
  __hip_bfloat162 h = __float22bfloat162_rn(float2{a, b});
  union { __hip_bfloat162 h; unsigned u; } x; x.h = h;
  return x.u;
}

__device__ __forceinline__ float blo(unsigned u) {
  union { unsigned u; float f; } x; x.u = u << 16; return x.f;
}
__device__ __forceinline__ float bhi(unsigned u) {
  union { unsigned u; float f; } x; x.u = u & 0xffff0000u; return x.f;
}

// sigma: swap bits 2 and 3 of a token index (involution, within 16-token
// groups). K stored at row sigma(t) makes the attn S^T C-layout's e[] order
// coincide with the 32x32x16 PV A-operand key order -> zero-shuffle K=16 PV.
__device__ __forceinline__ int sigma23(int t) {
  return (t & ~12) | ((t & 4) << 1) | ((t & 8) >> 1);
}

// XOR-swizzled ushort index into a [64][64] (128 B/row) LDS tile.
// byte_off within row ^= (row&7)<<4. With pre-swizzled global staging
// (source 16B-slot = (l&7)^(l>>3)) the staging write is lane-linear and
// all b128 frag reads distribute exactly 8 lanes per 16B slot.
__device__ __forceinline__ int swz64(int row, int colbyte) {
  return row * 64 + ((colbyte ^ ((row & 7) << 4)) >> 1);
}

// Single fused cast: x (1M uint4) + Wq/Wk/Wv (-> wqkv) + Wo (-> wob).
__global__ __launch_bounds__(256) void cast_all(const float* __restrict__ x,
                                                const float* __restrict__ Wq,
                                                const float* __restrict__ Wk,
                                                const float* __restrict__ Wv,
                                                const float* __restrict__ Wo,
                                                ushort* __restrict__ xb,
                                                ushort* __restrict__ wqkv,
                                                ushort* __restrict__ wob) {
  int idx = blockIdx.x * 256 + threadIdx.x;  // 0 .. 2M-1 (uint4 units)
  const float* in;
  uint2* out;
  if (idx < (1 << 20)) {
    in = x; out = (uint2*)xb;
  } else {
    int j = idx - (1 << 20);
    int w = j >> 18;            // 0..3
    idx = j & 0x3FFFF;          // 256K uint4 per weight
    switch (w) {
      case 0: in = Wq; out = (uint2*)wqkv; break;
      case 1: in = Wk; out = (uint2*)(wqkv) + (1 << 18); break;
      case 2: in = Wv; out = (uint2*)(wqkv) + (2 << 18); break;
      default: in = Wo; out = (uint2*)wob; break;
    }
  }
  float4 v = ((const float4*)in)[idx];
  uint2 o; o.x = pk2(v.x, v.y); o.y = pk2(v.z, v.w);
  out[idx] = o;
}

// Fused QKV projection: A = xb (4096x1024 bf16), Bw = wqkv (3072x1024 bf16).
// 128x128 tile, BK=64. 512-thread blocks (8 waves, 2Mx4N wave grid, 64x32
// wave tile) -> 16 waves/CU at 64 KB dbuf. K tokens stored at sigma23-
// permuted rows; Q and V^T unchanged.
// n<1024 -> Q (scaled), <2048 -> K, else -> V^T (packed b64 stores along t).
__global__ __launch_bounds__(512, 2) void gemm_qkv(const ushort* __restrict__ A,
                                                   const ushort* __restrict__ Bw,
                                                   ushort* __restrict__ Qh,
                                                   ushort* __restrict__ Kh,
                                                   ushort* __restrict__ Vth,
                                                   float qscale) {
  constexpr int K = 1024;
  const int bm = blockIdx.y * 128;
  const int bn = blockIdx.x * 128;
  const int tid = threadIdx.x;        // 0..511
  const int wave = tid >> 6;          // 0..7
  const int lane = tid & 63;
  const int l16 = lane & 15;
  const int quad = lane >> 4;

  __shared__ ushort As[2][128 * 64];   // 32 KB (dbuf)
  __shared__ ushort Bs[2][128 * 64];   // 32 KB (dbuf)

  const int wm = (wave & 1) * 64;      // 2 M-waves
  const int wn = (wave >> 1) * 32;     // 4 N-waves

  f32x4 acc[4][2];
#pragma unroll
  for (int r = 0; r < 4; ++r)
#pragma unroll
    for (int c = 0; c < 2; ++c) acc[r][c] = (f32x4){0.f, 0.f, 0.f, 0.f};

  // staging: per instruction round, 512 lanes x 16B = 64 rows x 128B.
  const int srow = wave * 8 + (lane >> 3);            // 0..63
  const int csw = (((lane & 7) ^ (lane >> 3)) << 3);  // pre-swizzled col (ushorts)

  // prologue: tile 0 -> buf 0
#pragma unroll
  for (int j = 0; j < 2; ++j) {
    async_cp16(A  + (size_t)(bm + j * 64 + srow) * K + csw, &As[0][(j * 64 + wave * 8) * 64]);
    async_cp16(Bw + (size_t)(bn + j * 64 + srow) * K + csw, &Bs[0][(j * 64 + wave * 8) * 64]);
  }

  constexpr int NIT = K / 64;  // 16
  for (int kt = 0; kt < NIT; ++kt) {
    __syncthreads();  // vmcnt(0) drain: tile kt landed; prior reads of buf^1 done
    const int buf = kt & 1;
    if (kt + 1 < NIT) {
      const int k0 = (kt + 1) * 64;
#pragma unroll
      for (int j = 0; j < 2; ++j) {
        async_cp16(A  + (size_t)(bm + j * 64 + srow) * K + k0 + csw, &As[buf ^ 1][(j * 64 + wave * 8) * 64]);
        async_cp16(Bw + (size_t)(bn + j * 64 + srow) * K + k0 + csw, &Bs[buf ^ 1][(j * 64 + wave * 8) * 64]);
      }
    }

    bf16x8 a[2][4], b[2][2];
#pragma unroll
    for (int ks = 0; ks < 2; ++ks) {
#pragma unroll
      for (int r = 0; r < 4; ++r)
        a[ks][r] = *(const bf16x8*)(&As[buf][swz64(wm + r * 16 + l16, ks * 64 + quad * 16)]);
#pragma unroll
      for (int c = 0; c < 2; ++c)
        b[ks][c] = *(const bf16x8*)(&Bs[buf][swz64(wn + c * 16 + l16, ks * 64 + quad * 16)]);
    }
#pragma unroll
    for (int ks = 0; ks < 2; ++ks)
#pragma unroll
      for (int r = 0; r < 4; ++r)
#pragma unroll
        for (int c = 0; c < 2; ++c)
          acc[r][c] = __builtin_amdgcn_mfma_f32_16x16x32_bf16(a[ks][r], b[ks][c], acc[r][c], 0, 0, 0);
  }

#pragma unroll
  for (int r = 0; r < 4; ++r) {
#pragma unroll
    for (int c = 0; c < 2; ++c) {
      int ncol = bn + wn + c * 16 + l16;   // w uniform per (block,wave,c)
      int w = ncol >> 10;
      int f = ncol & 1023;
      int h = f >> 6, d = f & 63;
      if (w == 2) {
        // V^T: 4 consecutive tokens per lane -> one b64 store (unpermuted)
        int m0 = bm + wm + r * 16 + quad * 4;
        int b = m0 >> 11, t0 = m0 & 2047;
        uint2 pp;
        pp.x = pk2(acc[r][c][0], acc[r][c][1]);
        pp.y = pk2(acc[r][c][2], acc[r][c][3]);
        *(uint2*)(&Vth[((size_t)(b * 1024 + f) << 11) + t0]) = pp;
      } else {
#pragma unroll
        for (int rr = 0; rr < 4; ++rr) {
          float v = acc[r][c][rr];
          int m = bm + wm + r * 16 + quad * 4 + rr;
          int b = m >> 11, t = m & 2047;
          if (w == 0)
            Qh[((size_t)(b * 16 + h) * SEQ + t) * 64 + d] = f2b(v * qscale);
          else
            Kh[((size_t)(b * 16 + h) * SEQ + sigma23(t)) * 64 + d] = f2b(v);
        }
      }
    }
  }
}

// Output projection with FUSED recombine (R26): A[m][k] = ctx = (O1+O2)/
// (l1+l2) computed on the fly during A-staging. For a 64x64 A K-tile at
// k0 = kt*64, h = kt is FIXED, so the tile maps to contiguous O rows
// [(b*16+h)*2048 + t]*64 + d. T14 split staging: O1/O2/l regs for tile kt+1
// loaded at kt-1 (HBM latency hidden under a full compute phase), converted
// + ds_written (swizzled, b128, 8-lanes/slot conflict-free) at kt top right
// after the barrier. Saves the recombine dispatch + 16 MB of HBM round-trip.
__global__ __launch_bounds__(256) void gemm_out(const ushort* __restrict__ O1,
                                                const ushort* __restrict__ O2,
                                                const float* __restrict__ l1,
                                                const float* __restrict__ l2,
                                                const ushort* __restrict__ Bw,
                                                float* __restrict__ out) {
  constexpr int K = 1024;
  const int bm = blockIdx.y * 64;
  const int bn = blockIdx.x * 128;
  const int tid = threadIdx.x;
  const int wave = tid >> 6;
  const int lane = tid & 63;
  const int l16 = lane & 15;
  const int quad = lane >> 4;

  __shared__ ushort As[2][64 * 64];    // 16 KB (dbuf)
  __shared__ ushort Bs[2][128 * 64];   // 32 KB (dbuf)

  const int wm = (wave & 1) * 32;
  const int wn = (wave >> 1) * 64;

  f32x4 acc[2][4];
#pragma unroll
  for (int r = 0; r < 2; ++r)
#pragma unroll
    for (int c = 0; c < 4; ++c) acc[r][c] = (f32x4){0.f, 0.f, 0.f, 0.f};

  const int srow = wave * 8 + (lane >> 3);            // 0..31
  const int slot = lane & 7;                          // global 16B slot
  const int csw = ((slot ^ (lane >> 3)) << 3);        // pre-swizzled col (B DMA)

  // A-staging register state (tile kt+1): 2 rows/thread (j*32 + srow)
  uint4 a1[2], a2[2];
  float lv[2];

  // row bases are loop-invariant per j; only h varies with kt
  size_t rb[2];  // (b*16)*2048 + t  (add h*2048 per tile)
  {
#pragma unroll
    for (int j = 0; j < 2; ++j) {
      int m = bm + j * 32 + srow;
      int b = m >> 11, t = m & 2047;
      rb[j] = (size_t)(b * 16) * SEQ + t;
    }
  }

#define LOAD_A(h)                                                         \
  {                                                                       \
    _Pragma("unroll")                                                     \
    for (int j = 0; j < 2; ++j) {                                         \
      size_t rowbase = rb[j] + (size_t)(h) * SEQ;                         \
      a1[j] = *(const uint4*)(O1 + rowbase * 64 + slot * 8);              \
      a2[j] = *(const uint4*)(O2 + rowbase * 64 + slot * 8);              \
      lv[j] = l1[rowbase] + l2[rowbase];                                  \
    }                                                                     \
  }

#define WRITE_A(bufi)                                                     \
  {                                                                       \
    _Pragma("unroll")                                                     \
    for (int j = 0; j < 2; ++j) {                                         \
      float linv = 1.f / lv[j];                                           \
      uint4 res;                                                          \
      unsigned* ap = (unsigned*)&a1[j];                                   \
      unsigned* bp = (unsigned*)&a2[j];                                   \
      unsigned* rp = (unsigned*)&res;                                     \
      _Pragma("unroll")                                                   \
      for (int i = 0; i < 4; ++i)                                         \
        rp[i] = pk2((blo(ap[i]) + blo(bp[i])) * linv,                     \
                    (bhi(ap[i]) + bhi(bp[i])) * linv);                    \
      *(uint4*)(&As[bufi][swz64(j * 32 + srow, slot * 16)]) = res;        \
    }                                                                     \
  }

  // prologue: tile 0 staged synchronously; B DMA tile 0; preload tile 1 regs
  LOAD_A(0);
  WRITE_A(0);
#pragma unroll
  for (int j = 0; j < 4; ++j)
    async_cp16(Bw + (size_t)(bn + j * 32 + srow) * K + csw, &Bs[0][(j * 32 + wave * 8) * 64]);
  LOAD_A(1);

  constexpr int NIT = K / 64;  // 16
  for (int kt = 0; kt < NIT; ++kt) {
    __syncthreads();  // Bs[buf] landed (vmcnt0); all waves done with buf^1
    const int buf = kt & 1;
    if (kt + 1 < NIT) {
      WRITE_A(buf ^ 1);          // tile kt+1 (regs loaded at kt-1)
      const int k0 = (kt + 1) * 64;
#pragma unroll
      for (int j = 0; j < 4; ++j)
        async_cp16(Bw + (size_t)(bn + j * 32 + srow) * K + k0 + csw, &Bs[buf ^ 1][(j * 32 + wave * 8) * 64]);
    }
    if (kt + 2 < NIT) LOAD_A(kt + 2);

    bf16x8 a[2][2], b[2][4];
#pragma unroll
    for (int ks = 0; ks < 2; ++ks) {
#pragma unroll
      for (int r = 0; r < 2; ++r)
        a[ks][r] = *(const bf16x8*)(&As[buf][swz64(wm + r * 16 + l16, ks * 64 + quad * 16)]);
#pragma unroll
      for (int c = 0; c < 4; ++c)
        b[ks][c] = *(const bf16x8*)(&Bs[buf][swz64(wn + c * 16 + l16, ks * 64 + quad * 16)]);
    }
#pragma unroll
    for (int ks = 0; ks < 2; ++ks)
#pragma unroll
      for (int r = 0; r < 2; ++r)
#pragma unroll
        for (int c = 0; c < 4; ++c)
          acc[r][c] = __builtin_amdgcn_mfma_f32_16x16x32_bf16(a[ks][r], b[ks][c], acc[r][c], 0, 0, 0);
  }

#pragma unroll
  for (int r = 0; r < 2; ++r)
#pragma unroll
    for (int c = 0; c < 4; ++c)
#pragma unroll
      for (int rr = 0; rr < 4; ++rr) {
        int m = bm + wm + r * 16 + quad * 4 + rr;
        int n = bn + wn + c * 16 + l16;
        out[(size_t)m * D_MODEL + n] = acc[r][c][rr];
      }
#undef LOAD_A
#undef WRITE_A
}

// Flash attention (R24 structure, reverted from R25's regression): 2-way
// K-split, 4 waves x 32 q-rows, 32 KB K/V dbuf staged by global_load_lds,
// 32x32x16 QK^T, in-register softmax, zero-shuffle K=16 PV via the sigma23
// producer-side key permutation (K row r holds key sigma(r); S^T C-row
// composed with sigma gives exactly the PV A-operand k-slot order).
__global__ __launch_bounds__(256, 2) void attn_kernel(const ushort* __restrict__ Qh,
                                                      const ushort* __restrict__ Kh,
                                                      const ushort* __restrict__ Vth,
                                                      ushort* __restrict__ O1,
                                                      ushort* __restrict__ O2,
                                                      float* __restrict__ l1,
                                                      float* __restrict__ l2) {
  const int id = blockIdx.x;
  const int stream = id & 63;       // bh*2 + half
  const int qb = id >> 6;           // 0..15
  const int bh = stream >> 1;
  const int half = stream & 1;
  const int q0 = qb * 128;
  ushort* __restrict__ Op = half ? O2 : O1;
  float* __restrict__ lp = half ? l2 : l1;

  const int tid = threadIdx.x;
  const int wave = tid >> 6;
  const int lane = tid & 63;
  const int l31 = lane & 31;
  const int hi = lane >> 5;

  __shared__ ushort KVbuf[2][2][64 * 64];  // 32 KB: [buf][0=K,1=V^T], swizzled

  // Q frags (B-op of QK): col = l31 = q, k = d = dc*16 + hi*8 + j
  bf16x8 qf[4];
#pragma unroll
  for (int dc = 0; dc < 4; ++dc)
    qf[dc] = *(const bf16x8*)(Qh + ((size_t)bh * SEQ + q0 + wave * 32 + l31) * 64 + dc * 16 + hi * 8);

  f32x16 o0 = {0.f, 0.f, 0.f, 0.f, 0.f, 0.f, 0.f, 0.f,
               0.f, 0.f, 0.f, 0.f, 0.f, 0.f, 0.f, 0.f};
  f32x16 o1 = o0;
  float lacc = 0.f;

  // async staging geometry: wave fills chunks {2w,2w+1} (8 rows each);
  // source 16B-slot pre-swizzled so the lane-linear LDS write leaves data
  // at the swz64 position.
  const int chunk = wave * 2;
  const int r8 = lane >> 3;
  const int csw = (((lane & 7) ^ r8) << 3);   // ushort offset within 64
  const ushort* kbase = Kh + ((size_t)bh * SEQ + half * 1024) * 64;
  const ushort* vbase = Vth + (size_t)bh * 64 * SEQ + half * 1024;
  const ushort* ksrc = kbase + (size_t)(chunk * 8 + r8) * 64 + csw;   // +kt*4096
  const ushort* vsrc = vbase + (size_t)(chunk * 8 + r8) * SEQ + csw;  // +kt*64

  // prologue: tile 0 -> buf 0
  async_cp16(ksrc,           &KVbuf[0][0][chunk * 512]);
  async_cp16(ksrc + 8 * 64,  &KVbuf[0][0][(chunk + 1) * 512]);
  async_cp16(vsrc,           &KVbuf[0][1][chunk * 512]);
  async_cp16(vsrc + 8 * SEQ, &KVbuf[0][1][(chunk + 1) * 512]);

  constexpr int NIT = 1024 / 64;  // 16
  for (int kt = 0; kt < NIT; ++kt) {
    __syncthreads();  // drains vmcnt: tile kt landed; prior reads of buf^1 done
    const int buf = kt & 1;
    if (kt + 1 < NIT) {
      const ushort* ks = ksrc + (size_t)(kt + 1) * 64 * 64;
      const ushort* vs = vsrc + (kt + 1) * 64;
      async_cp16(ks,           &KVbuf[buf ^ 1][0][chunk * 512]);
      async_cp16(ks + 8 * 64,  &KVbuf[buf ^ 1][0][(chunk + 1) * 512]);
      async_cp16(vs,           &KVbuf[buf ^ 1][1][chunk * 512]);
      async_cp16(vs + 8 * SEQ, &KVbuf[buf ^ 1][1][(chunk + 1) * 512]);
    }
    const ushort* Kt = KVbuf[buf][0];
    const ushort* Vt = KVbuf[buf][1];

#pragma unroll
    for (int kt2 = 0; kt2 < 2; ++kt2) {
      // QK^T: A = K (row = sigma(key) slot = kt2*32 + l31, k = d), 4 d-chunks
      bf16x8 ka0 = *(const bf16x8*)(&Kt[swz64(kt2 * 32 + l31, 0 * 32 + hi * 16)]);
      bf16x8 ka1 = *(const bf16x8*)(&Kt[swz64(kt2 * 32 + l31, 1 * 32 + hi * 16)]);
      bf16x8 ka2 = *(const bf16x8*)(&Kt[swz64(kt2 * 32 + l31, 2 * 32 + hi * 16)]);
      bf16x8 ka3 = *(const bf16x8*)(&Kt[swz64(kt2 * 32 + l31, 3 * 32 + hi * 16)]);
      f32x16 z = {0.f, 0.f, 0.f, 0.f, 0.f, 0.f, 0.f, 0.f,
                  0.f, 0.f, 0.f, 0.f, 0.f, 0.f, 0.f, 0.f};
      z = __builtin_amdgcn_mfma_f32_32x32x16_bf16(ka0, qf[0], z, 0, 0, 0);
      z = __builtin_amdgcn_mfma_f32_32x32x16_bf16(ka1, qf[1], z, 0, 0, 0);
      z = __builtin_amdgcn_mfma_f32_32x32x16_bf16(ka2, qf[2], z, 0, 0, 0);
      z = __builtin_amdgcn_mfma_f32_32x32x16_bf16(ka3, qf[3], z, 0, 0, 0);

      float e[16];
#pragma unroll
      for (int r = 0; r < 16; ++r) e[r] = __builtin_amdgcn_exp2f(z[r]);
      lacc += (((e[0] + e[1]) + (e[2] + e[3])) + ((e[4] + e[5]) + (e[6] + e[7])))
            + (((e[8] + e[9]) + (e[10] + e[11])) + ((e[12] + e[13]) + (e[14] + e[15])));

      // PV, zero-shuffle K=16: e[8lw+j] sits at C-row (j&3)+8(j>>2)+4hi ->
      // key sigma(row) = 16lw + 8hi + j = A k-slot 8hi+j. Direct pack.
#pragma unroll
      for (int lw = 0; lw < 2; ++lw) {
        const int base = lw * 8;
        union { unsigned u[4]; bf16x8 v; } pu;
        pu.u[0] = pk2(e[base + 0], e[base + 1]);
        pu.u[1] = pk2(e[base + 2], e[base + 3]);
        pu.u[2] = pk2(e[base + 4], e[base + 5]);
        pu.u[3] = pk2(e[base + 6], e[base + 7]);
        const int wb = (kt2 * 2 + lw) * 32;  // window byte col in V^T
        bf16x8 vb0 = *(const bf16x8*)(&Vt[swz64(0 + l31, wb + hi * 16)]);
        bf16x8 vb1 = *(const bf16x8*)(&Vt[swz64(32 + l31, wb + hi * 16)]);
        o0 = __builtin_amdgcn_mfma_f32_32x32x16_bf16(pu.v, vb0, o0, 0, 0, 0);
        o1 = __builtin_amdgcn_mfma_f32_32x32x16_bf16(pu.v, vb1, o1, 0, 0, 0);
      }
    }
  }

  // l: lane and lane+32 hold complementary key-halves of the same q = l31.
  {
    float ltot = lacc + __shfl_xor(lacc, 32, 64);
    if (hi == 0)
      lp[(size_t)bh * SEQ + q0 + wave * 32 + l31] = ltot;
  }

  // O-store: scatter o into LDS [128][64] (q-row major), then coalesced
  // full-line uint4 copy-out. C layout: row q = (r&3)+8*(r>>2)+4*hi, col d.
  __syncthreads();  // all waves done with K/V LDS
  ushort* Ob = &KVbuf[0][0][0];  // 16 KB region
#pragma unroll
  for (int r = 0; r < 16; ++r) {
    int row = wave * 32 + (r & 3) + 8 * (r >> 2) + 4 * hi;
    Ob[row * 64 + l31] = f2b(o0[r]);
    Ob[row * 64 + 32 + l31] = f2b(o1[r]);
  }
  __syncthreads();  // O tile visible
  {
    uint4* dst = (uint4*)(Op + ((size_t)bh * SEQ + q0) * 64);
    const uint4* src = (const uint4*)Ob;
#pragma unroll
    for (int i = 0; i < 4; ++i)
      dst[i * 256 + tid] = src[i * 256 + tid];
  }
}

extern "C" void kernel_launch(void* const* d_in, const int* in_sizes, int n_in,
                              void* d_out, int out_size, void* d_ws, size_t ws_size,
                              hipStream_t stream) {
  const float* x  = (const float*)d_in[0];
  const float* Wq = (const float*)d_in[1];
  const float* Wk = (const float*)d_in[2];
  const float* Wv = (const float*)d_in[3];
  const float* Wo = (const float*)d_in[4];
  float* out = (float*)d_out;

  char* ws = (char*)d_ws;
  const size_t MB = 1 << 20;
  ushort* xb   = (ushort*)(ws);             // 8 MB (dead after gemm_qkv -> O2)
  ushort* wqkv = (ushort*)(ws +  8 * MB);   // 6 MB (dead after gemm_qkv -> l1/l2)
  ushort* wob  = (ushort*)(ws + 14 * MB);   // 2 MB (live until gemm_out)
  ushort* Qh   = (ushort*)(ws + 16 * MB);   // 8 MB (BH,T,64)
  ushort* Kh   = (ushort*)(ws + 24 * MB);   // 8 MB (BH,T,64)
  ushort* Vth  = (ushort*)(ws + 32 * MB);   // 8 MB (BH,64,T)

  // split-K partials (regions dead during attn/gemm_out):
  ushort* O1 = (ushort*)(ws + 40 * MB);     // former ctx region (gemm_out
                                            // both reads O1 and writes d_out,
                                            // so O1 must NOT alias d_out)
  ushort* O2 = xb;                          // xb region, dead after gemm_qkv
  float*  l1 = (float*)wqkv;                // 256 KB
  float*  l2 = (float*)(ws + 8 * MB + 256 * 1024);

  cast_all<<<8192, 256, 0, stream>>>(x, Wq, Wk, Wv, Wo, xb, wqkv, wob);

  const float qscale = 0.125f * 1.44269504089f;  // SCALE * log2(e)
  gemm_qkv<<<dim3(3072 / 128, 4096 / 128), 512, 0, stream>>>(xb, wqkv, Qh, Kh, Vth, qscale);

  // 1D grid, 1024 blocks: id = qb*64 + (bh*2+half) -> id%8 fixed per stream
  attn_kernel<<<(SEQ / 128) * BATCH * N_HEADS * 2, 256, 0, stream>>>(
      Qh, Kh, Vth, O1, O2, l1, l2);

  // recombine fused into gemm_out's A-staging (reads O1/O2/l directly)
  gemm_out<<<dim3(1024 / 128, 4096 / 64), 256, 0, stream>>>(O1, O2, l1, l2, wob, out);
}

// Round 16
// 191.841 us; speedup vs baseline: 1.0137x; 1.0137x over previous
//
#include <hip/hip_runtime.h>
#include <hip/hip_bf16.h>

#define D_MODEL 1024
#define N_HEADS 16
#define HEAD_DIM 64
#define SEQ 2048
#define BATCH 2

typedef __attribute__((ext_vector_type(8))) short bf16x8;
typedef __attribute__((ext_vector_type(4))) short bf16x4;
typedef __attribute__((ext_vector_type(4))) float f32x4;
typedef __attribute__((ext_vector_type(16))) float f32x16;

typedef __attribute__((address_space(3))) unsigned lds_uint;
typedef __attribute__((address_space(1))) const unsigned global_cuint;

__device__ __forceinline__ void async_cp16(const ushort* g, ushort* l) {
  __builtin_amdgcn_global_load_lds((global_cuint*)g, (lds_uint*)l, 16, 0, 0);
}

__device__ __forceinline__ ushort f2b(float f) {
  union { float f; unsigned u; } x; x.f = f;
  unsigned r = x.u + 0x7fffu + ((x.u >> 16) & 1u);
  return (ushort)(r >> 16);
}

// packed f32x2 -> bf16x2; low word = a
__device__ __forceinline__ unsigned pk2(float a, float b) {
  __hip_bfloat162 h = __float22bfloat162_rn(float2{a, b});
  union { __hip_bfloat162 h; unsigned u; } x; x.h = h;
  return x.u;
}

__device__ __forceinline__ float blo(unsigned u) {
  union { unsigned u; float f; } x; x.u = u << 16; return x.f;
}
__device__ __forceinline__ float bhi(unsigned u) {
  union { unsigned u; float f; } x; x.u = u & 0xffff0000u; return x.f;
}

// sigma: swap bits 2 and 3 of a token index (involution, within 16-token
// groups). K stored at row sigma(t) makes the attn S^T C-layout's e[] order
// coincide with the 32x32x16 PV A-operand key order -> zero-shuffle K=16 PV.
__device__ __forceinline__ int sigma23(int t) {
  return (t & ~12) | ((t & 4) << 1) | ((t & 8) >> 1);
}

// XOR-swizzled ushort index into a [64][64] (128 B/row) LDS tile.
// byte_off within row ^= (row&7)<<4. With pre-swizzled global staging
// (source 16B-slot = (l&7)^(l>>3)) the staging write is lane-linear and
// all b128 frag reads distribute exactly 8 lanes per 16B slot.
__device__ __forceinline__ int swz64(int row, int colbyte) {
  return row * 64 + ((colbyte ^ ((row & 7) << 4)) >> 1);
}

// Single fused cast: x (1M uint4) + Wq/Wk/Wv (-> wqkv) + Wo (-> wob).
__global__ __launch_bounds__(256) void cast_all(const float* __restrict__ x,
                                                const float* __restrict__ Wq,
                                                const float* __restrict__ Wk,
                                                const float* __restrict__ Wv,
                                                const float* __restrict__ Wo,
                                                ushort* __restrict__ xb,
                                                ushort* __restrict__ wqkv,
                                                ushort* __restrict__ wob) {
  int idx = blockIdx.x * 256 + threadIdx.x;  // 0 .. 2M-1 (uint4 units)
  const float* in;
  uint2* out;
  if (idx < (1 << 20)) {
    in = x; out = (uint2*)xb;
  } else {
    int j = idx - (1 << 20);
    int w = j >> 18;            // 0..3
    idx = j & 0x3FFFF;          // 256K uint4 per weight
    switch (w) {
      case 0: in = Wq; out = (uint2*)wqkv; break;
      case 1: in = Wk; out = (uint2*)(wqkv) + (1 << 18); break;
      case 2: in = Wv; out = (uint2*)(wqkv) + (2 << 18); break;
      default: in = Wo; out = (uint2*)wob; break;
    }
  }
  float4 v = ((const float4*)in)[idx];
  uint2 o; o.x = pk2(v.x, v.y); o.y = pk2(v.z, v.w);
  out[idx] = o;
}

// Fused QKV projection: A = xb (4096x1024 bf16), Bw = wqkv (3072x1024 bf16).
// 128x128 tile, BK=64. 512-thread blocks (8 waves, 2Mx4N wave grid, 64x32
// wave tile) -> 16 waves/CU at 64 KB dbuf. K tokens stored at sigma23-
// permuted rows; Q and V^T unchanged.
// n<1024 -> Q (scaled), <2048 -> K, else -> V^T (packed b64 stores along t).
__global__ __launch_bounds__(512, 2) void gemm_qkv(const ushort* __restrict__ A,
                                                   const ushort* __restrict__ Bw,
                                                   ushort* __restrict__ Qh,
                                                   ushort* __restrict__ Kh,
                                                   ushort* __restrict__ Vth,
                                                   float qscale) {
  constexpr int K = 1024;
  const int bm = blockIdx.y * 128;
  const int bn = blockIdx.x * 128;
  const int tid = threadIdx.x;        // 0..511
  const int wave = tid >> 6;          // 0..7
  const int lane = tid & 63;
  const int l16 = lane & 15;
  const int quad = lane >> 4;

  __shared__ ushort As[2][128 * 64];   // 32 KB (dbuf)
  __shared__ ushort Bs[2][128 * 64];   // 32 KB (dbuf)

  const int wm = (wave & 1) * 64;      // 2 M-waves
  const int wn = (wave >> 1) * 32;     // 4 N-waves

  f32x4 acc[4][2];
#pragma unroll
  for (int r = 0; r < 4; ++r)
#pragma unroll
    for (int c = 0; c < 2; ++c) acc[r][c] = (f32x4){0.f, 0.f, 0.f, 0.f};

  // staging: per instruction round, 512 lanes x 16B = 64 rows x 128B.
  const int srow = wave * 8 + (lane >> 3);            // 0..63
  const int csw = (((lane & 7) ^ (lane >> 3)) << 3);  // pre-swizzled col (ushorts)

  // prologue: tile 0 -> buf 0
#pragma unroll
  for (int j = 0; j < 2; ++j) {
    async_cp16(A  + (size_t)(bm + j * 64 + srow) * K + csw, &As[0][(j * 64 + wave * 8) * 64]);
    async_cp16(Bw + (size_t)(bn + j * 64 + srow) * K + csw, &Bs[0][(j * 64 + wave * 8) * 64]);
  }

  constexpr int NIT = K / 64;  // 16
  for (int kt = 0; kt < NIT; ++kt) {
    __syncthreads();  // vmcnt(0) drain: tile kt landed; prior reads of buf^1 done
    const int buf = kt & 1;
    if (kt + 1 < NIT) {
      const int k0 = (kt + 1) * 64;
#pragma unroll
      for (int j = 0; j < 2; ++j) {
        async_cp16(A  + (size_t)(bm + j * 64 + srow) * K + k0 + csw, &As[buf ^ 1][(j * 64 + wave * 8) * 64]);
        async_cp16(Bw + (size_t)(bn + j * 64 + srow) * K + k0 + csw, &Bs[buf ^ 1][(j * 64 + wave * 8) * 64]);
      }
    }

    bf16x8 a[2][4], b[2][2];
#pragma unroll
    for (int ks = 0; ks < 2; ++ks) {
#pragma unroll
      for (int r = 0; r < 4; ++r)
        a[ks][r] = *(const bf16x8*)(&As[buf][swz64(wm + r * 16 + l16, ks * 64 + quad * 16)]);
#pragma unroll
      for (int c = 0; c < 2; ++c)
        b[ks][c] = *(const bf16x8*)(&Bs[buf][swz64(wn + c * 16 + l16, ks * 64 + quad * 16)]);
    }
#pragma unroll
    for (int ks = 0; ks < 2; ++ks)
#pragma unroll
      for (int r = 0; r < 4; ++r)
#pragma unroll
        for (int c = 0; c < 2; ++c)
          acc[r][c] = __builtin_amdgcn_mfma_f32_16x16x32_bf16(a[ks][r], b[ks][c], acc[r][c], 0, 0, 0);
  }

#pragma unroll
  for (int r = 0; r < 4; ++r) {
#pragma unroll
    for (int c = 0; c < 2; ++c) {
      int ncol = bn + wn + c * 16 + l16;   // w uniform per (block,wave,c)
      int w = ncol >> 10;
      int f = ncol & 1023;
      int h = f >> 6, d = f & 63;
      if (w == 2) {
        // V^T: 4 consecutive tokens per lane -> one b64 store (unpermuted)
        int m0 = bm + wm + r * 16 + quad * 4;
        int b = m0 >> 11, t0 = m0 & 2047;
        uint2 pp;
        pp.x = pk2(acc[r][c][0], acc[r][c][1]);
        pp.y = pk2(acc[r][c][2], acc[r][c][3]);
        *(uint2*)(&Vth[((size_t)(b * 1024 + f) << 11) + t0]) = pp;
      } else {
#pragma unroll
        for (int rr = 0; rr < 4; ++rr) {
          float v = acc[r][c][rr];
          int m = bm + wm + r * 16 + quad * 4 + rr;
          int b = m >> 11, t = m & 2047;
          if (w == 0)
            Qh[((size_t)(b * 16 + h) * SEQ + t) * 64 + d] = f2b(v * qscale);
          else
            Kh[((size_t)(b * 16 + h) * SEQ + sigma23(t)) * 64 + d] = f2b(v);
        }
      }
    }
  }
}

// Output projection: A = ctx (4096x1024 bf16), Bw = wob, fp32 out.
// 64x128 tile, BK=64. Dbuf + swizzle (R15). Recombine kept as its own
// dispatch: R26's fusion attempt cost +19us (redundant per-bn recombine +
// barrier-drained A prefetch) — reverted.
__global__ __launch_bounds__(256) void gemm_out(const ushort* __restrict__ A,
                                                const ushort* __restrict__ Bw,
                                                float* __restrict__ out) {
  constexpr int K = 1024;
  const int bm = blockIdx.y * 64;
  const int bn = blockIdx.x * 128;
  const int tid = threadIdx.x;
  const int wave = tid >> 6;
  const int lane = tid & 63;
  const int l16 = lane & 15;
  const int quad = lane >> 4;

  __shared__ ushort As[2][64 * 64];    // 16 KB (dbuf)
  __shared__ ushort Bs[2][128 * 64];   // 32 KB (dbuf)

  const int wm = (wave & 1) * 32;
  const int wn = (wave >> 1) * 64;

  f32x4 acc[2][4];
#pragma unroll
  for (int r = 0; r < 2; ++r)
#pragma unroll
    for (int c = 0; c < 4; ++c) acc[r][c] = (f32x4){0.f, 0.f, 0.f, 0.f};

  const int srow = wave * 8 + (lane >> 3);
  const int csw = (((lane & 7) ^ (lane >> 3)) << 3);  // pre-swizzled col (ushorts)

  // prologue: tile 0 -> buf 0
#pragma unroll
  for (int j = 0; j < 2; ++j)
    async_cp16(A + (size_t)(bm + j * 32 + srow) * K + csw, &As[0][(j * 32 + wave * 8) * 64]);
#pragma unroll
  for (int j = 0; j < 4; ++j)
    async_cp16(Bw + (size_t)(bn + j * 32 + srow) * K + csw, &Bs[0][(j * 32 + wave * 8) * 64]);

  constexpr int NIT = K / 64;  // 16
  for (int kt = 0; kt < NIT; ++kt) {
    __syncthreads();
    const int buf = kt & 1;
    if (kt + 1 < NIT) {
      const int k0 = (kt + 1) * 64;
#pragma unroll
      for (int j = 0; j < 2; ++j)
        async_cp16(A + (size_t)(bm + j * 32 + srow) * K + k0 + csw, &As[buf ^ 1][(j * 32 + wave * 8) * 64]);
#pragma unroll
      for (int j = 0; j < 4; ++j)
        async_cp16(Bw + (size_t)(bn + j * 32 + srow) * K + k0 + csw, &Bs[buf ^ 1][(j * 32 + wave * 8) * 64]);
    }

    bf16x8 a[2][2], b[2][4];
#pragma unroll
    for (int ks = 0; ks < 2; ++ks) {
#pragma unroll
      for (int r = 0; r < 2; ++r)
        a[ks][r] = *(const bf16x8*)(&As[buf][swz64(wm + r * 16 + l16, ks * 64 + quad * 16)]);
#pragma unroll
      for (int c = 0; c < 4; ++c)
        b[ks][c] = *(const bf16x8*)(&Bs[buf][swz64(wn + c * 16 + l16, ks * 64 + quad * 16)]);
    }
#pragma unroll
    for (int ks = 0; ks < 2; ++ks)
#pragma unroll
      for (int r = 0; r < 2; ++r)
#pragma unroll
        for (int c = 0; c < 4; ++c)
          acc[r][c] = __builtin_amdgcn_mfma_f32_16x16x32_bf16(a[ks][r], b[ks][c], acc[r][c], 0, 0, 0);
  }

#pragma unroll
  for (int r = 0; r < 2; ++r)
#pragma unroll
    for (int c = 0; c < 4; ++c)
#pragma unroll
      for (int rr = 0; rr < 4; ++rr) {
        int m = bm + wm + r * 16 + quad * 4 + rr;
        int n = bn + wn + c * 16 + l16;
        out[(size_t)m * D_MODEL + n] = acc[r][c][rr];
      }
}

// Flash attention, R27 = R24 + ILP/latency-chain attack:
//  - QK: z split into 2 independent 2-chains (za, zb) + vector add (chain
//    latency ~128 -> ~80 cyc per kt2).
//  - PV: accumulators split per lw (o0a/o0b, o1a/o1b; summed once at end) ->
//    per-accumulator MFMA chain depth halves (64 -> 32 over the loop).
//  - s_setprio(1) around the MFMA clusters (T5; 2 independent blocks/CU give
//    the scheduler something to arbitrate; measured +4-7% on attn in m191).
// VGPR ~110 (<128, wave tier unchanged). Everything else identical to R24.
__global__ __launch_bounds__(256, 2) void attn_kernel(const ushort* __restrict__ Qh,
                                                      const ushort* __restrict__ Kh,
                                                      const ushort* __restrict__ Vth,
                                                      ushort* __restrict__ O1,
                                                      ushort* __restrict__ O2,
                                                      float* __restrict__ l1,
                                                      float* __restrict__ l2) {
  const int id = blockIdx.x;
  const int stream = id & 63;       // bh*2 + half
  const int qb = id >> 6;           // 0..15
  const int bh = stream >> 1;
  const int half = stream & 1;
  const int q0 = qb * 128;
  ushort* __restrict__ Op = half ? O2 : O1;
  float* __restrict__ lp = half ? l2 : l1;

  const int tid = threadIdx.x;
  const int wave = tid >> 6;
  const int lane = tid & 63;
  const int l31 = lane & 31;
  const int hi = lane >> 5;

  __shared__ ushort KVbuf[2][2][64 * 64];  // 32 KB: [buf][0=K,1=V^T], swizzled

  // Q frags (B-op of QK): col = l31 = q, k = d = dc*16 + hi*8 + j
  bf16x8 qf[4];
#pragma unroll
  for (int dc = 0; dc < 4; ++dc)
    qf[dc] = *(const bf16x8*)(Qh + ((size_t)bh * SEQ + q0 + wave * 32 + l31) * 64 + dc * 16 + hi * 8);

  const f32x16 zero16 = {0.f, 0.f, 0.f, 0.f, 0.f, 0.f, 0.f, 0.f,
                         0.f, 0.f, 0.f, 0.f, 0.f, 0.f, 0.f, 0.f};
  f32x16 o0a = zero16, o0b = zero16, o1a = zero16, o1b = zero16;
  float lacc = 0.f;

  // async staging geometry: wave fills chunks {2w,2w+1} (8 rows each);
  // source 16B-slot pre-swizzled so the lane-linear LDS write leaves data
  // at the swz64 position.
  const int chunk = wave * 2;
  const int r8 = lane >> 3;
  const int csw = (((lane & 7) ^ r8) << 3);   // ushort offset within 64
  const ushort* kbase = Kh + ((size_t)bh * SEQ + half * 1024) * 64;
  const ushort* vbase = Vth + (size_t)bh * 64 * SEQ + half * 1024;
  const ushort* ksrc = kbase + (size_t)(chunk * 8 + r8) * 64 + csw;   // +kt*4096
  const ushort* vsrc = vbase + (size_t)(chunk * 8 + r8) * SEQ + csw;  // +kt*64

  // prologue: tile 0 -> buf 0
  async_cp16(ksrc,           &KVbuf[0][0][chunk * 512]);
  async_cp16(ksrc + 8 * 64,  &KVbuf[0][0][(chunk + 1) * 512]);
  async_cp16(vsrc,           &KVbuf[0][1][chunk * 512]);
  async_cp16(vsrc + 8 * SEQ, &KVbuf[0][1][(chunk + 1) * 512]);

  constexpr int NIT = 1024 / 64;  // 16
  for (int kt = 0; kt < NIT; ++kt) {
    __syncthreads();  // drains vmcnt: tile kt landed; prior reads of buf^1 done
    const int buf = kt & 1;
    if (kt + 1 < NIT) {
      const ushort* ks = ksrc + (size_t)(kt + 1) * 64 * 64;
      const ushort* vs = vsrc + (kt + 1) * 64;
      async_cp16(ks,           &KVbuf[buf ^ 1][0][chunk * 512]);
      async_cp16(ks + 8 * 64,  &KVbuf[buf ^ 1][0][(chunk + 1) * 512]);
      async_cp16(vs,           &KVbuf[buf ^ 1][1][chunk * 512]);
      async_cp16(vs + 8 * SEQ, &KVbuf[buf ^ 1][1][(chunk + 1) * 512]);
    }
    const ushort* Kt = KVbuf[buf][0];
    const ushort* Vt = KVbuf[buf][1];

#pragma unroll
    for (int kt2 = 0; kt2 < 2; ++kt2) {
      // QK^T: A = K (row = sigma(key) slot = kt2*32 + l31, k = d), 4 d-chunks
      bf16x8 ka0 = *(const bf16x8*)(&Kt[swz64(kt2 * 32 + l31, 0 * 32 + hi * 16)]);
      bf16x8 ka1 = *(const bf16x8*)(&Kt[swz64(kt2 * 32 + l31, 1 * 32 + hi * 16)]);
      bf16x8 ka2 = *(const bf16x8*)(&Kt[swz64(kt2 * 32 + l31, 2 * 32 + hi * 16)]);
      bf16x8 ka3 = *(const bf16x8*)(&Kt[swz64(kt2 * 32 + l31, 3 * 32 + hi * 16)]);
      // two independent 2-chains halve the QK latency chain
      __builtin_amdgcn_s_setprio(1);
      f32x16 za = __builtin_amdgcn_mfma_f32_32x32x16_bf16(ka0, qf[0], zero16, 0, 0, 0);
      f32x16 zb = __builtin_amdgcn_mfma_f32_32x32x16_bf16(ka2, qf[2], zero16, 0, 0, 0);
      za = __builtin_amdgcn_mfma_f32_32x32x16_bf16(ka1, qf[1], za, 0, 0, 0);
      zb = __builtin_amdgcn_mfma_f32_32x32x16_bf16(ka3, qf[3], zb, 0, 0, 0);
      __builtin_amdgcn_s_setprio(0);
      f32x16 z = za + zb;

      float e[16];
#pragma unroll
      for (int r = 0; r < 16; ++r) e[r] = __builtin_amdgcn_exp2f(z[r]);
      lacc += (((e[0] + e[1]) + (e[2] + e[3])) + ((e[4] + e[5]) + (e[6] + e[7])))
            + (((e[8] + e[9]) + (e[10] + e[11])) + ((e[12] + e[13]) + (e[14] + e[15])));

      // PV, zero-shuffle K=16: e[8lw+j] sits at C-row (j&3)+8(j>>2)+4hi ->
      // key sigma(row) = 16lw + 8hi + j = A k-slot 8hi+j. Direct pack.
      // Per-lw accumulators halve the PV chain depth.
#pragma unroll
      for (int lw = 0; lw < 2; ++lw) {
        const int base = lw * 8;
        union { unsigned u[4]; bf16x8 v; } pu;
        pu.u[0] = pk2(e[base + 0], e[base + 1]);
        pu.u[1] = pk2(e[base + 2], e[base + 3]);
        pu.u[2] = pk2(e[base + 4], e[base + 5]);
        pu.u[3] = pk2(e[base + 6], e[base + 7]);
        const int wb = (kt2 * 2 + lw) * 32;  // window byte col in V^T
        bf16x8 vb0 = *(const bf16x8*)(&Vt[swz64(0 + l31, wb + hi * 16)]);
        bf16x8 vb1 = *(const bf16x8*)(&Vt[swz64(32 + l31, wb + hi * 16)]);
        __builtin_amdgcn_s_setprio(1);
        if (lw == 0) {
          o0a = __builtin_amdgcn_mfma_f32_32x32x16_bf16(pu.v, vb0, o0a, 0, 0, 0);
          o1a = __builtin_amdgcn_mfma_f32_32x32x16_bf16(pu.v, vb1, o1a, 0, 0, 0);
        } else {
          o0b = __builtin_amdgcn_mfma_f32_32x32x16_bf16(pu.v, vb0, o0b, 0, 0, 0);
          o1b = __builtin_amdgcn_mfma_f32_32x32x16_bf16(pu.v, vb1, o1b, 0, 0, 0);
        }
        __builtin_amdgcn_s_setprio(0);
      }
    }
  }

  f32x16 o0 = o0a + o0b;
  f32x16 o1 = o1a + o1b;

  // l: lane and lane+32 hold complementary key-halves of the same q = l31.
  {
    float ltot = lacc + __shfl_xor(lacc, 32, 64);
    if (hi == 0)
      lp[(size_t)bh * SEQ + q0 + wave * 32 + l31] = ltot;
  }

  // O-store: scatter o into LDS [128][64] (q-row major), then coalesced
  // full-line uint4 copy-out. C layout: row q = (r&3)+8*(r>>2)+4*hi, col d.
  __syncthreads();  // all waves done with K/V LDS
  ushort* Ob = &KVbuf[0][0][0];  // 16 KB region
#pragma unroll
  for (int r = 0; r < 16; ++r) {
    int row = wave * 32 + (r & 3) + 8 * (r >> 2) + 4 * hi;
    Ob[row * 64 + l31] = f2b(o0[r]);
    Ob[row * 64 + 32 + l31] = f2b(o1[r]);
  }
  __syncthreads();  // O tile visible
  {
    uint4* dst = (uint4*)(Op + ((size_t)bh * SEQ + q0) * 64);
    const uint4* src = (const uint4*)Ob;
#pragma unroll
    for (int i = 0; i < 4; ++i)
      dst[i * 256 + tid] = src[i * 256 + tid];
  }
}

// ctx = (O1 + O2) / (l1 + l2), routed to (B, T, D_MODEL) bf16
__global__ __launch_bounds__(256) void recombine(const ushort* __restrict__ O1,
                                                 const ushort* __restrict__ O2,
                                                 const float* __restrict__ l1,
                                                 const float* __restrict__ l2,
                                                 ushort* __restrict__ ctx) {
  int idx = blockIdx.x * 256 + threadIdx.x;   // over (BH*T*64)/8 uint4 chunks
  int row = idx >> 3;                         // bh*SEQ + t
  int d8 = idx & 7;
  uint4 a = ((const uint4*)O1)[idx];
  uint4 b = ((const uint4*)O2)[idx];
  float linv = 1.f / (l1[row] + l2[row]);
  uint4 res;
  unsigned* ap = (unsigned*)&a;
  unsigned* bp = (unsigned*)&b;
  unsigned* rp = (unsigned*)&res;
#pragma unroll
  for (int i = 0; i < 4; ++i) {
    float lo = (blo(ap[i]) + blo(bp[i])) * linv;
    float hi = (bhi(ap[i]) + bhi(bp[i])) * linv;
    rp[i] = pk2(lo, hi);
  }
  int bh = row >> 11, t = row & 2047;
  int bb = bh >> 4, h = bh & 15;
  ((uint4*)ctx)[(size_t)(bb * SEQ + t) * 128 + h * 8 + d8] = res;
}

extern "C" void kernel_launch(void* const* d_in, const int* in_sizes, int n_in,
                              void* d_out, int out_size, void* d_ws, size_t ws_size,
                              hipStream_t stream) {
  const float* x  = (const float*)d_in[0];
  const float* Wq = (const float*)d_in[1];
  const float* Wk = (const float*)d_in[2];
  const float* Wv = (const float*)d_in[3];
  const float* Wo = (const float*)d_in[4];
  float* out = (float*)d_out;

  char* ws = (char*)d_ws;
  const size_t MB = 1 << 20;
  ushort* xb   = (ushort*)(ws);             // 8 MB (dead after gemm_qkv -> O2)
  ushort* wqkv = (ushort*)(ws +  8 * MB);   // 6 MB (dead after gemm_qkv -> l1/l2)
  ushort* wob  = (ushort*)(ws + 14 * MB);   // 2 MB (live until gemm_out)
  ushort* Qh   = (ushort*)(ws + 16 * MB);   // 8 MB (BH,T,64)
  ushort* Kh   = (ushort*)(ws + 24 * MB);   // 8 MB (BH,T,64)
  ushort* Vth  = (ushort*)(ws + 32 * MB);   // 8 MB (BH,64,T)
  ushort* ctx  = (ushort*)(ws + 40 * MB);   // 8 MB (B,T,D)

  // split-K partials (regions dead during attn):
  ushort* O1 = (ushort*)d_out;              // 8 MB of the 16 MB output buffer
  ushort* O2 = xb;                          // xb region, dead after gemm_qkv
  float*  l1 = (float*)wqkv;                // 256 KB
  float*  l2 = (float*)(ws + 8 * MB + 256 * 1024);

  cast_all<<<8192, 256, 0, stream>>>(x, Wq, Wk, Wv, Wo, xb, wqkv, wob);

  const float qscale = 0.125f * 1.44269504089f;  // SCALE * log2(e)
  gemm_qkv<<<dim3(3072 / 128, 4096 / 128), 512, 0, stream>>>(xb, wqkv, Qh, Kh, Vth, qscale);

  // 1D grid, 1024 blocks: id = qb*64 + (bh*2+half) -> id%8 fixed per stream
  attn_kernel<<<(SEQ / 128) * BATCH * N_HEADS * 2, 256, 0, stream>>>(
      Qh, Kh, Vth, O1, O2, l1, l2);

  recombine<<<(BATCH * N_HEADS * SEQ * 64 / 8) / 256, 256, 0, stream>>>(O1, O2, l1, l2, ctx);

  gemm_out<<<dim3(1024 / 128, 4096 / 64), 256, 0, stream>>>(ctx, wob, out);
}

// Round 17
// 182.659 us; speedup vs baseline: 1.0647x; 1.0503x over previous
//
#include <hip/hip_runtime.h>
#include <hip/hip_bf16.h>

#define D_MODEL 1024
#define N_HEADS 16
#define HEAD_DIM 64
#define SEQ 2048
#define BATCH 2

typedef __attribute__((ext_vector_type(8))) short bf16x8;
typedef __attribute__((ext_vector_type(4))) short bf16x4;
typedef __attribute__((ext_vector_type(4))) float f32x4;
typedef __attribute__((ext_vector_type(16))) float f32x16;

typedef __attribute__((address_space(3))) unsigned lds_uint;
typedef __attribute__((address_space(1))) const unsigned global_cuint;

__device__ __forceinline__ void async_cp16(const ushort* g, ushort* l) {
  __builtin_amdgcn_global_load_lds((global_cuint*)g, (lds_uint*)l, 16, 0, 0);
}

__device__ __forceinline__ ushort f2b(float f) {
  union { float f; unsigned u; } x; x.f = f;
  unsigned r = x.u + 0x7fffu + ((x.u >> 16) & 1u);
  return (ushort)(r >> 16);
}

// packed f32x2 -> bf16x2; low word = a
__device__ __forceinline__ unsigned pk2(float a, float b) {
  __hip_bfloat162 h = __float22bfloat162_rn(float2{a, b});
  union { __hip_bfloat162 h; unsigned u; } x; x.h = h;
  return x.u;
}

__device__ __forceinline__ float blo(unsigned u) {
  union { unsigned u; float f; } x; x.u = u << 16; return x.f;
}
__device__ __forceinline__ float bhi(unsigned u) {
  union { unsigned u; float f; } x; x.u = u & 0xffff0000u; return x.f;
}

// sigma: swap bits 2 and 3 of a token index (involution, within 16-token
// groups). K stored at row sigma(t) makes the attn S^T C-layout's e[] order
// coincide with the 32x32x16 PV A-operand key order -> zero-shuffle K=16 PV.
__device__ __forceinline__ int sigma23(int t) {
  return (t & ~12) | ((t & 4) << 1) | ((t & 8) >> 1);
}

// XOR-swizzled ushort index into a [64][64] (128 B/row) LDS tile.
// byte_off within row ^= (row&7)<<4. With pre-swizzled global staging
// (source 16B-slot = (l&7)^(l>>3)) the staging write is lane-linear and
// all b128 frag reads distribute exactly 8 lanes per 16B slot.
__device__ __forceinline__ int swz64(int row, int colbyte) {
  return row * 64 + ((colbyte ^ ((row & 7) << 4)) >> 1);
}

// Single fused cast: x (1M uint4) + Wq/Wk/Wv (-> wqkv) + Wo (-> wob).
__global__ __launch_bounds__(256) void cast_all(const float* __restrict__ x,
                                                const float* __restrict__ Wq,
                                                const float* __restrict__ Wk,
                                                const float* __restrict__ Wv,
                                                const float* __restrict__ Wo,
                                                ushort* __restrict__ xb,
                                                ushort* __restrict__ wqkv,
                                                ushort* __restrict__ wob) {
  int idx = blockIdx.x * 256 + threadIdx.x;  // 0 .. 2M-1 (uint4 units)
  const float* in;
  uint2* out;
  if (idx < (1 << 20)) {
    in = x; out = (uint2*)xb;
  } else {
    int j = idx - (1 << 20);
    int w = j >> 18;            // 0..3
    idx = j & 0x3FFFF;          // 256K uint4 per weight
    switch (w) {
      case 0: in = Wq; out = (uint2*)wqkv; break;
      case 1: in = Wk; out = (uint2*)(wqkv) + (1 << 18); break;
      case 2: in = Wv; out = (uint2*)(wqkv) + (2 << 18); break;
      default: in = Wo; out = (uint2*)wob; break;
    }
  }
  float4 v = ((const float4*)in)[idx];
  uint2 o; o.x = pk2(v.x, v.y); o.y = pk2(v.z, v.w);
  out[idx] = o;
}

// Fused QKV projection: A = xb (4096x1024 bf16), Bw = wqkv (3072x1024 bf16).
// 128x128 tile, BK=64. 512-thread blocks (8 waves, 2Mx4N wave grid, 64x32
// wave tile) -> 16 waves/CU at 64 KB dbuf. K tokens stored at sigma23-
// permuted rows; Q and V^T unchanged.
// n<1024 -> Q (scaled), <2048 -> K, else -> V^T (packed b64 stores along t).
__global__ __launch_bounds__(512, 2) void gemm_qkv(const ushort* __restrict__ A,
                                                   const ushort* __restrict__ Bw,
                                                   ushort* __restrict__ Qh,
                                                   ushort* __restrict__ Kh,
                                                   ushort* __restrict__ Vth,
                                                   float qscale) {
  constexpr int K = 1024;
  const int bm = blockIdx.y * 128;
  const int bn = blockIdx.x * 128;
  const int tid = threadIdx.x;        // 0..511
  const int wave = tid >> 6;          // 0..7
  const int lane = tid & 63;
  const int l16 = lane & 15;
  const int quad = lane >> 4;

  __shared__ ushort As[2][128 * 64];   // 32 KB (dbuf)
  __shared__ ushort Bs[2][128 * 64];   // 32 KB (dbuf)

  const int wm = (wave & 1) * 64;      // 2 M-waves
  const int wn = (wave >> 1) * 32;     // 4 N-waves

  f32x4 acc[4][2];
#pragma unroll
  for (int r = 0; r < 4; ++r)
#pragma unroll
    for (int c = 0; c < 2; ++c) acc[r][c] = (f32x4){0.f, 0.f, 0.f, 0.f};

  // staging: per instruction round, 512 lanes x 16B = 64 rows x 128B.
  const int srow = wave * 8 + (lane >> 3);            // 0..63
  const int csw = (((lane & 7) ^ (lane >> 3)) << 3);  // pre-swizzled col (ushorts)

  // prologue: tile 0 -> buf 0
#pragma unroll
  for (int j = 0; j < 2; ++j) {
    async_cp16(A  + (size_t)(bm + j * 64 + srow) * K + csw, &As[0][(j * 64 + wave * 8) * 64]);
    async_cp16(Bw + (size_t)(bn + j * 64 + srow) * K + csw, &Bs[0][(j * 64 + wave * 8) * 64]);
  }

  constexpr int NIT = K / 64;  // 16
  for (int kt = 0; kt < NIT; ++kt) {
    __syncthreads();  // vmcnt(0) drain: tile kt landed; prior reads of buf^1 done
    const int buf = kt & 1;
    if (kt + 1 < NIT) {
      const int k0 = (kt + 1) * 64;
#pragma unroll
      for (int j = 0; j < 2; ++j) {
        async_cp16(A  + (size_t)(bm + j * 64 + srow) * K + k0 + csw, &As[buf ^ 1][(j * 64 + wave * 8) * 64]);
        async_cp16(Bw + (size_t)(bn + j * 64 + srow) * K + k0 + csw, &Bs[buf ^ 1][(j * 64 + wave * 8) * 64]);
      }
    }

    bf16x8 a[2][4], b[2][2];
#pragma unroll
    for (int ks = 0; ks < 2; ++ks) {
#pragma unroll
      for (int r = 0; r < 4; ++r)
        a[ks][r] = *(const bf16x8*)(&As[buf][swz64(wm + r * 16 + l16, ks * 64 + quad * 16)]);
#pragma unroll
      for (int c = 0; c < 2; ++c)
        b[ks][c] = *(const bf16x8*)(&Bs[buf][swz64(wn + c * 16 + l16, ks * 64 + quad * 16)]);
    }
#pragma unroll
    for (int ks = 0; ks < 2; ++ks)
#pragma unroll
      for (int r = 0; r < 4; ++r)
#pragma unroll
        for (int c = 0; c < 2; ++c)
          acc[r][c] = __builtin_amdgcn_mfma_f32_16x16x32_bf16(a[ks][r], b[ks][c], acc[r][c], 0, 0, 0);
  }

#pragma unroll
  for (int r = 0; r < 4; ++r) {
#pragma unroll
    for (int c = 0; c < 2; ++c) {
      int ncol = bn + wn + c * 16 + l16;   // w uniform per (block,wave,c)
      int w = ncol >> 10;
      int f = ncol & 1023;
      int h = f >> 6, d = f & 63;
      if (w == 2) {
        // V^T: 4 consecutive tokens per lane -> one b64 store (unpermuted)
        int m0 = bm + wm + r * 16 + quad * 4;
        int b = m0 >> 11, t0 = m0 & 2047;
        uint2 pp;
        pp.x = pk2(acc[r][c][0], acc[r][c][1]);
        pp.y = pk2(acc[r][c][2], acc[r][c][3]);
        *(uint2*)(&Vth[((size_t)(b * 1024 + f) << 11) + t0]) = pp;
      } else {
#pragma unroll
        for (int rr = 0; rr < 4; ++rr) {
          float v = acc[r][c][rr];
          int m = bm + wm + r * 16 + quad * 4 + rr;
          int b = m >> 11, t = m & 2047;
          if (w == 0)
            Qh[((size_t)(b * 16 + h) * SEQ + t) * 64 + d] = f2b(v * qscale);
          else
            Kh[((size_t)(b * 16 + h) * SEQ + sigma23(t)) * 64 + d] = f2b(v);
        }
      }
    }
  }
}

// Output projection: A = ctx (4096x1024 bf16), Bw = wob, fp32 out.
// 64x128 tile, BK=64. Dbuf + swizzle (R15). Standalone recombine is gone:
// attn writes normalized ctx directly (R28).
__global__ __launch_bounds__(256) void gemm_out(const ushort* __restrict__ A,
                                                const ushort* __restrict__ Bw,
                                                float* __restrict__ out) {
  constexpr int K = 1024;
  const int bm = blockIdx.y * 64;
  const int bn = blockIdx.x * 128;
  const int tid = threadIdx.x;
  const int wave = tid >> 6;
  const int lane = tid & 63;
  const int l16 = lane & 15;
  const int quad = lane >> 4;

  __shared__ ushort As[2][64 * 64];    // 16 KB (dbuf)
  __shared__ ushort Bs[2][128 * 64];   // 32 KB (dbuf)

  const int wm = (wave & 1) * 32;
  const int wn = (wave >> 1) * 64;

  f32x4 acc[2][4];
#pragma unroll
  for (int r = 0; r < 2; ++r)
#pragma unroll
    for (int c = 0; c < 4; ++c) acc[r][c] = (f32x4){0.f, 0.f, 0.f, 0.f};

  const int srow = wave * 8 + (lane >> 3);
  const int csw = (((lane & 7) ^ (lane >> 3)) << 3);  // pre-swizzled col (ushorts)

  // prologue: tile 0 -> buf 0
#pragma unroll
  for (int j = 0; j < 2; ++j)
    async_cp16(A + (size_t)(bm + j * 32 + srow) * K + csw, &As[0][(j * 32 + wave * 8) * 64]);
#pragma unroll
  for (int j = 0; j < 4; ++j)
    async_cp16(Bw + (size_t)(bn + j * 32 + srow) * K + csw, &Bs[0][(j * 32 + wave * 8) * 64]);

  constexpr int NIT = K / 64;  // 16
  for (int kt = 0; kt < NIT; ++kt) {
    __syncthreads();
    const int buf = kt & 1;
    if (kt + 1 < NIT) {
      const int k0 = (kt + 1) * 64;
#pragma unroll
      for (int j = 0; j < 2; ++j)
        async_cp16(A + (size_t)(bm + j * 32 + srow) * K + k0 + csw, &As[buf ^ 1][(j * 32 + wave * 8) * 64]);
#pragma unroll
      for (int j = 0; j < 4; ++j)
        async_cp16(Bw + (size_t)(bn + j * 32 + srow) * K + k0 + csw, &Bs[buf ^ 1][(j * 32 + wave * 8) * 64]);
    }

    bf16x8 a[2][2], b[2][4];
#pragma unroll
    for (int ks = 0; ks < 2; ++ks) {
#pragma unroll
      for (int r = 0; r < 2; ++r)
        a[ks][r] = *(const bf16x8*)(&As[buf][swz64(wm + r * 16 + l16, ks * 64 + quad * 16)]);
#pragma unroll
      for (int c = 0; c < 4; ++c)
        b[ks][c] = *(const bf16x8*)(&Bs[buf][swz64(wn + c * 16 + l16, ks * 64 + quad * 16)]);
    }
#pragma unroll
    for (int ks = 0; ks < 2; ++ks)
#pragma unroll
      for (int r = 0; r < 2; ++r)
#pragma unroll
        for (int c = 0; c < 4; ++c)
          acc[r][c] = __builtin_amdgcn_mfma_f32_16x16x32_bf16(a[ks][r], b[ks][c], acc[r][c], 0, 0, 0);
  }

#pragma unroll
  for (int r = 0; r < 2; ++r)
#pragma unroll
    for (int c = 0; c < 4; ++c)
#pragma unroll
      for (int rr = 0; rr < 4; ++rr) {
        int m = bm + wm + r * 16 + quad * 4 + rr;
        int n = bn + wn + c * 16 + l16;
        out[(size_t)m * D_MODEL + n] = acc[r][c][rr];
      }
}

// Flash attention, R28: R24 inner loop (verbatim — its ~48us was the best of
// 4 structural variants; R18/R25/R27 all falsified alternatives), but FULL-K
// per block (NIT=32): no split-K partials, no recombine dispatch. The block
// holds the complete row-sum l at loop end, normalizes in f32, and writes
// bf16 ctx directly (saves ~10us dispatch + ~32 MB HBM round-trip; R26
// showed consumer-side fusion loses — this is producer-side elimination).
// l bridge: ltot lives at q=l31 but o-rows are q=(r&3)+8(r>>2)+4hi, so l
// goes through a 128-float LDS array; scatter reads are same-address
// broadcasts (conflict-free, same-wave in-order => no extra barrier).
// Grid 512 = 16 qb x 32 bh; id%8 = bh%8 -> 4 KV streams/XCD = 1 MB < L2.
__global__ __launch_bounds__(256, 2) void attn_kernel(const ushort* __restrict__ Qh,
                                                      const ushort* __restrict__ Kh,
                                                      const ushort* __restrict__ Vth,
                                                      ushort* __restrict__ ctx) {
  const int id = blockIdx.x;
  const int bh = id & 31;           // 0..31
  const int qb = id >> 5;           // 0..15
  const int q0 = qb * 128;
  const int b = bh >> 4, h = bh & 15;

  const int tid = threadIdx.x;
  const int wave = tid >> 6;
  const int lane = tid & 63;
  const int l31 = lane & 31;
  const int hi = lane >> 5;

  __shared__ ushort KVbuf[2][2][64 * 64];  // 32 KB: [buf][0=K,1=V^T], swizzled
  __shared__ float Ls[128];                // per-q row sums (l bridge)

  // Q frags (B-op of QK): col = l31 = q, k = d = dc*16 + hi*8 + j
  bf16x8 qf[4];
#pragma unroll
  for (int dc = 0; dc < 4; ++dc)
    qf[dc] = *(const bf16x8*)(Qh + ((size_t)bh * SEQ + q0 + wave * 32 + l31) * 64 + dc * 16 + hi * 8);

  f32x16 o0 = {0.f, 0.f, 0.f, 0.f, 0.f, 0.f, 0.f, 0.f,
               0.f, 0.f, 0.f, 0.f, 0.f, 0.f, 0.f, 0.f};
  f32x16 o1 = o0;
  float lacc = 0.f;

  // async staging geometry: wave fills chunks {2w,2w+1} (8 rows each);
  // source 16B-slot pre-swizzled so the lane-linear LDS write leaves data
  // at the swz64 position.
  const int chunk = wave * 2;
  const int r8 = lane >> 3;
  const int csw = (((lane & 7) ^ r8) << 3);   // ushort offset within 64
  const ushort* kbase = Kh + (size_t)bh * SEQ * 64;
  const ushort* vbase = Vth + (size_t)bh * 64 * SEQ;
  const ushort* ksrc = kbase + (size_t)(chunk * 8 + r8) * 64 + csw;   // +kt*4096
  const ushort* vsrc = vbase + (size_t)(chunk * 8 + r8) * SEQ + csw;  // +kt*64

  // prologue: tile 0 -> buf 0
  async_cp16(ksrc,           &KVbuf[0][0][chunk * 512]);
  async_cp16(ksrc + 8 * 64,  &KVbuf[0][0][(chunk + 1) * 512]);
  async_cp16(vsrc,           &KVbuf[0][1][chunk * 512]);
  async_cp16(vsrc + 8 * SEQ, &KVbuf[0][1][(chunk + 1) * 512]);

  constexpr int NIT = SEQ / 64;  // 32 (full K per block)
  for (int kt = 0; kt < NIT; ++kt) {
    __syncthreads();  // drains vmcnt: tile kt landed; prior reads of buf^1 done
    const int buf = kt & 1;
    if (kt + 1 < NIT) {
      const ushort* ks = ksrc + (size_t)(kt + 1) * 64 * 64;
      const ushort* vs = vsrc + (kt + 1) * 64;
      async_cp16(ks,           &KVbuf[buf ^ 1][0][chunk * 512]);
      async_cp16(ks + 8 * 64,  &KVbuf[buf ^ 1][0][(chunk + 1) * 512]);
      async_cp16(vs,           &KVbuf[buf ^ 1][1][chunk * 512]);
      async_cp16(vs + 8 * SEQ, &KVbuf[buf ^ 1][1][(chunk + 1) * 512]);
    }
    const ushort* Kt = KVbuf[buf][0];
    const ushort* Vt = KVbuf[buf][1];

#pragma unroll
    for (int kt2 = 0; kt2 < 2; ++kt2) {
      // QK^T: A = K (row = sigma(key) slot = kt2*32 + l31, k = d), 4 d-chunks
      bf16x8 ka0 = *(const bf16x8*)(&Kt[swz64(kt2 * 32 + l31, 0 * 32 + hi * 16)]);
      bf16x8 ka1 = *(const bf16x8*)(&Kt[swz64(kt2 * 32 + l31, 1 * 32 + hi * 16)]);
      bf16x8 ka2 = *(const bf16x8*)(&Kt[swz64(kt2 * 32 + l31, 2 * 32 + hi * 16)]);
      bf16x8 ka3 = *(const bf16x8*)(&Kt[swz64(kt2 * 32 + l31, 3 * 32 + hi * 16)]);
      f32x16 z = {0.f, 0.f, 0.f, 0.f, 0.f, 0.f, 0.f, 0.f,
                  0.f, 0.f, 0.f, 0.f, 0.f, 0.f, 0.f, 0.f};
      z = __builtin_amdgcn_mfma_f32_32x32x16_bf16(ka0, qf[0], z, 0, 0, 0);
      z = __builtin_amdgcn_mfma_f32_32x32x16_bf16(ka1, qf[1], z, 0, 0, 0);
      z = __builtin_amdgcn_mfma_f32_32x32x16_bf16(ka2, qf[2], z, 0, 0, 0);
      z = __builtin_amdgcn_mfma_f32_32x32x16_bf16(ka3, qf[3], z, 0, 0, 0);

      float e[16];
#pragma unroll
      for (int r = 0; r < 16; ++r) e[r] = __builtin_amdgcn_exp2f(z[r]);
      lacc += (((e[0] + e[1]) + (e[2] + e[3])) + ((e[4] + e[5]) + (e[6] + e[7])))
            + (((e[8] + e[9]) + (e[10] + e[11])) + ((e[12] + e[13]) + (e[14] + e[15])));

      // PV, zero-shuffle K=16: e[8lw+j] sits at C-row (j&3)+8(j>>2)+4hi ->
      // key sigma(row) = 16lw + 8hi + j = A k-slot 8hi+j. Direct pack.
#pragma unroll
      for (int lw = 0; lw < 2; ++lw) {
        const int base = lw * 8;
        union { unsigned u[4]; bf16x8 v; } pu;
        pu.u[0] = pk2(e[base + 0], e[base + 1]);
        pu.u[1] = pk2(e[base + 2], e[base + 3]);
        pu.u[2] = pk2(e[base + 4], e[base + 5]);
        pu.u[3] = pk2(e[base + 6], e[base + 7]);
        const int wb = (kt2 * 2 + lw) * 32;  // window byte col in V^T
        bf16x8 vb0 = *(const bf16x8*)(&Vt[swz64(0 + l31, wb + hi * 16)]);
        bf16x8 vb1 = *(const bf16x8*)(&Vt[swz64(32 + l31, wb + hi * 16)]);
        o0 = __builtin_amdgcn_mfma_f32_32x32x16_bf16(pu.v, vb0, o0, 0, 0, 0);
        o1 = __builtin_amdgcn_mfma_f32_32x32x16_bf16(pu.v, vb1, o1, 0, 0, 0);
      }
    }
  }

  // full row sums -> LDS (lane and lane+32 hold complementary key-halves of
  // the same q = l31; after the xor both hold the total).
  {
    float ltot = lacc + __shfl_xor(lacc, 32, 64);
    if (hi == 0)
      Ls[wave * 32 + l31] = ltot;
  }

  // O-store: normalize in f32 (l via same-wave LDS broadcast; write above is
  // ordered before these reads by the in-order LDS pipe), scatter into LDS
  // [128][64] (q-row major), then coalesced uint4 copy-out to ctx (B,T,D).
  __syncthreads();  // all waves done with K/V LDS
  ushort* Ob = &KVbuf[0][0][0];  // 16 KB region
#pragma unroll
  for (int r = 0; r < 16; ++r) {
    int row = wave * 32 + (r & 3) + 8 * (r >> 2) + 4 * hi;
    float linv = 1.f / Ls[row];
    Ob[row * 64 + l31] = f2b(o0[r] * linv);
    Ob[row * 64 + 32 + l31] = f2b(o1[r] * linv);
  }
  __syncthreads();  // O tile visible
  {
    uint4* dst = (uint4*)ctx;
    const uint4* src = (const uint4*)Ob;
#pragma unroll
    for (int i = 0; i < 4; ++i) {
      int idx = i * 256 + tid;
      int row = idx >> 3, d8 = idx & 7;
      dst[(size_t)(b * SEQ + q0 + row) * 128 + h * 8 + d8] = src[idx];
    }
  }
}

extern "C" void kernel_launch(void* const* d_in, const int* in_sizes, int n_in,
                              void* d_out, int out_size, void* d_ws, size_t ws_size,
                              hipStream_t stream) {
  const float* x  = (const float*)d_in[0];
  const float* Wq = (const float*)d_in[1];
  const float* Wk = (const float*)d_in[2];
  const float* Wv = (const float*)d_in[3];
  const float* Wo = (const float*)d_in[4];
  float* out = (float*)d_out;

  char* ws = (char*)d_ws;
  const size_t MB = 1 << 20;
  ushort* xb   = (ushort*)(ws);             // 8 MB
  ushort* wqkv = (ushort*)(ws +  8 * MB);   // 6 MB
  ushort* wob  = (ushort*)(ws + 14 * MB);   // 2 MB (live until gemm_out)
  ushort* Qh   = (ushort*)(ws + 16 * MB);   // 8 MB (BH,T,64)
  ushort* Kh   = (ushort*)(ws + 24 * MB);   // 8 MB (BH,T,64; sigma23 rows)
  ushort* Vth  = (ushort*)(ws + 32 * MB);   // 8 MB (BH,64,T)
  ushort* ctx  = (ushort*)(ws + 40 * MB);   // 8 MB (B,T,D) — attn writes directly

  cast_all<<<8192, 256, 0, stream>>>(x, Wq, Wk, Wv, Wo, xb, wqkv, wob);

  const float qscale = 0.125f * 1.44269504089f;  // SCALE * log2(e)
  gemm_qkv<<<dim3(3072 / 128, 4096 / 128), 512, 0, stream>>>(xb, wqkv, Qh, Kh, Vth, qscale);

  // full-K attn, 512 blocks: id = qb*32 + bh -> id%8 = bh%8 (XCD affinity)
  attn_kernel<<<(SEQ / 128) * BATCH * N_HEADS, 256, 0, stream>>>(Qh, Kh, Vth, ctx);

  gemm_out<<<dim3(1024 / 128, 4096 / 64), 256, 0, stream>>>(ctx, wob, out);
}